// Round 1
// 4698.847 us; speedup vs baseline: 5.1508x; 5.1508x over previous
//
#include <hip/hip_runtime.h>
#include <hip/hip_bf16.h>
#include <cstdint>
#include <cstddef>

#define T_STEPS 2048
#define BATCH 16
#define DIM 1024

typedef _Float16 f16;
typedef _Float16 f16x2 __attribute__((ext_vector_type(2)));
typedef _Float16 f16x4 __attribute__((ext_vector_type(4)));
typedef _Float16 f16x8 __attribute__((ext_vector_type(8)));
typedef float f32x4 __attribute__((ext_vector_type(4)));

#define SCOPE_AGENT __HIP_MEMORY_SCOPE_AGENT

// Sentinel: f16 NaN pattern. tanh output is in [-1,1] so a valid packed pair
// can never equal 0x7FFF7FFF. Producers store whole dwords, so each dword is
// either all-sentinel or fully valid (no tearing within a dword).
#define SENT32 0x7FFF7FFFu

// ---------------- workspace layout (bytes) ----------------
static const size_t OFF_U      = 0;          // 1024 f32
static const size_t OFF_V      = 4096;       // 1024 f32
static const size_t OFF_Y      = 8192;       // 1024 f32
static const size_t OFF_SCALE  = 12288;      // f32
static const size_t OFF_PART   = 16384;      // 16*1024 f32 (64 KB)
static const size_t OFF_WX16   = 262144;     // 2 MB
static const size_t OFF_WG16   = 2359296;    // 2 MB
static const size_t OFF_X16    = 4456448;    // 64 MB
static const size_t OFF_PX16   = 71565312;   // 64 MB
static const size_t OFF_H16    = 138674176;  // 2049*16*1024*2 -> total ~205.8 MB

__device__ __forceinline__ float fdot2f(f16x2 a, f16x2 b, float c) {
#if __has_builtin(__builtin_amdgcn_fdot2)
  return __builtin_amdgcn_fdot2(a, b, c, false);
#else
  return c + (float)a[0]*(float)b[0] + (float)a[1]*(float)b[1];
#endif
}

template <int CTRL>
__device__ __forceinline__ float dpp_add_f(float x) {
  int y = __builtin_amdgcn_update_dpp(0, __builtin_bit_cast(int, x), CTRL, 0xf, 0xf, true);
  return x + __builtin_bit_cast(float, y);
}
__device__ __forceinline__ float dpp_mov_xor1(float x) {
  int y = __builtin_amdgcn_update_dpp(0, __builtin_bit_cast(int, x), 0xB1, 0xf, 0xf, true);
  return __builtin_bit_cast(float, y);
}

__device__ __forceinline__ float fast_tanh(float x) {
  float xx = fminf(fmaxf(x, -15.f), 15.f);
  float e = __expf(2.f * xx);                     // v_exp_f32 path
  return 1.f - 2.f * __builtin_amdgcn_rcpf(e + 1.f);
}

// both dwords of an 8-byte chunk published?
__device__ __forceinline__ bool valid8(unsigned long long q) {
  return ((unsigned)q != SENT32) & ((unsigned)(q >> 32) != SENT32);
}

// ---------------- u = normalized RandomState(0).randn(1024) ----------------
__global__ __launch_bounds__(256) void k_ugen(float* __restrict__ u_out) {
  __shared__ unsigned st[624], nxt[624], outb[624];
  __shared__ double dbl[3120];
  __shared__ int flag[1560];
  __shared__ int map[512];
  __shared__ float ul[1024];
  __shared__ float red[256];
  const int tid = threadIdx.x;
  if (tid == 0) {
    st[0] = 0u;
    for (int i = 1; i < 624; ++i)
      st[i] = 1812433253u * (st[i-1] ^ (st[i-1] >> 30)) + (unsigned)i;
  }
  __syncthreads();
  for (int blk = 0; blk < 10; ++blk) {
    if (tid < 227) {
      int i = tid;
      unsigned y = (st[i] & 0x80000000u) | (st[i+1] & 0x7fffffffu);
      nxt[i] = st[i+397] ^ (y >> 1) ^ ((y & 1u) ? 0x9908b0dfu : 0u);
    }
    __syncthreads();
    if (tid < 227) {
      int i = 227 + tid;
      unsigned y = (st[i] & 0x80000000u) | (st[i+1] & 0x7fffffffu);
      nxt[i] = nxt[i-227] ^ (y >> 1) ^ ((y & 1u) ? 0x9908b0dfu : 0u);
    }
    __syncthreads();
    if (tid < 170) {
      int i = 454 + tid;
      unsigned lo = (i < 623) ? st[i+1] : nxt[0];
      unsigned y = (st[i] & 0x80000000u) | (lo & 0x7fffffffu);
      nxt[i] = nxt[i-227] ^ (y >> 1) ^ ((y & 1u) ? 0x9908b0dfu : 0u);
    }
    __syncthreads();
    for (int i = tid; i < 624; i += 256) {
      unsigned y = nxt[i];
      y ^= y >> 11; y ^= (y << 7) & 0x9d2c5680u; y ^= (y << 15) & 0xefc60000u; y ^= y >> 18;
      outb[i] = y;
    }
    __syncthreads();
    for (int i = tid; i < 312; i += 256) {
      unsigned a = outb[2*i] >> 5, bb = outb[2*i+1] >> 6;
      dbl[blk*312 + i] = ((double)a * 67108864.0 + (double)bb) * (1.0/9007199254740992.0);
    }
    for (int i = tid; i < 624; i += 256) st[i] = nxt[i];
    __syncthreads();
  }
  for (int j = tid; j < 1560; j += 256) {
    double x1 = 2.0*dbl[2*j] - 1.0, x2 = 2.0*dbl[2*j+1] - 1.0;
    double r2 = x1*x1 + x2*x2;
    flag[j] = (r2 < 1.0 && r2 != 0.0) ? 1 : 0;
  }
  __syncthreads();
  if (tid == 0) {
    int cnt = 0;
    for (int j = 0; j < 1560 && cnt < 512; ++j) if (flag[j]) map[cnt++] = j;
  }
  __syncthreads();
  for (int p = tid; p < 512; p += 256) {
    int j = map[p];
    double x1 = 2.0*dbl[2*j] - 1.0, x2 = 2.0*dbl[2*j+1] - 1.0;
    double r2 = x1*x1 + x2*x2;
    double f = sqrt(-2.0 * log(r2) / r2);
    ul[2*p]   = (float)(f * x2);
    ul[2*p+1] = (float)(f * x1);
  }
  __syncthreads();
  float ss = 0.f;
  for (int i = tid; i < 1024; i += 256) ss += ul[i]*ul[i];
  red[tid] = ss; __syncthreads();
  for (int s = 128; s > 0; s >>= 1) { if (tid < s) red[tid] += red[tid+s]; __syncthreads(); }
  float inv = 1.0f / sqrtf(red[0]);
  for (int i = tid; i < 1024; i += 256) u_out[i] = ul[i] * inv;
}

// ---------------- power iteration pieces ----------------
__global__ __launch_bounds__(256) void k_mvT(const float* __restrict__ W,
                                             const float* __restrict__ u,
                                             float* __restrict__ part) {
  const int c = blockIdx.x >> 2;
  const int j = (blockIdx.x & 3)*256 + threadIdx.x;
  const int i0 = c*64;
  float acc = 0.f;
  for (int i = 0; i < 64; ++i) acc += W[(size_t)(i0+i)*1024 + j] * u[i0+i];
  part[c*1024 + j] = acc;
}

__global__ __launch_bounds__(256) void k_norm_part(const float* __restrict__ part,
                                                   float* __restrict__ vout) {
  __shared__ float red[256];
  const int tid = threadIdx.x;
  float vals[4]; float ss = 0.f;
  for (int k = 0; k < 4; ++k) {
    int j = tid + k*256;
    float s = 0.f;
    for (int c = 0; c < 16; ++c) s += part[c*1024 + j];
    vals[k] = s; ss += s*s;
  }
  red[tid] = ss; __syncthreads();
  for (int s = 128; s > 0; s >>= 1) { if (tid < s) red[tid] += red[tid+s]; __syncthreads(); }
  float inv = 1.0f / (sqrtf(red[0]) + 1e-8f);
  for (int k = 0; k < 4; ++k) vout[tid + k*256] = vals[k]*inv;
}

__global__ __launch_bounds__(256) void k_mv_rows(const float* __restrict__ W,
                                                 const float* __restrict__ v,
                                                 float* __restrict__ y) {
  const int lane = threadIdx.x & 63, wave = threadIdx.x >> 6;
  const int row0 = blockIdx.x*16 + wave*4;
  const float4* vp = (const float4*)(v + lane*16);
  float4 vv0 = vp[0], vv1 = vp[1], vv2 = vp[2], vv3 = vp[3];
  float res = 0.f;
  for (int rr = 0; rr < 4; ++rr) {
    const float4* wp = (const float4*)(W + (size_t)(row0+rr)*1024 + lane*16);
    float4 w0 = wp[0], w1 = wp[1], w2 = wp[2], w3 = wp[3];
    float acc = w0.x*vv0.x + w0.y*vv0.y + w0.z*vv0.z + w0.w*vv0.w
              + w1.x*vv1.x + w1.y*vv1.y + w1.z*vv1.z + w1.w*vv1.w
              + w2.x*vv2.x + w2.y*vv2.y + w2.z*vv2.z + w2.w*vv2.w
              + w3.x*vv3.x + w3.y*vv3.y + w3.z*vv3.z + w3.w*vv3.w;
    #pragma unroll
    for (int off = 1; off < 64; off <<= 1) acc += __shfl_xor(acc, off, 64);
    res = (lane == rr) ? acc : res;
  }
  if (lane < 4) y[row0 + lane] = res;
}

__global__ __launch_bounds__(256) void k_norm_u(const float* __restrict__ y,
                                                float* __restrict__ u,
                                                float* __restrict__ scale_out) {
  __shared__ float red[256];
  const int tid = threadIdx.x;
  float ss = 0.f;
  for (int k = 0; k < 4; ++k) { float t = y[tid + k*256]; ss += t*t; }
  red[tid] = ss; __syncthreads();
  for (int s = 128; s > 0; s >>= 1) { if (tid < s) red[tid] += red[tid+s]; __syncthreads(); }
  float norm = sqrtf(red[0]);
  float inv = 1.0f / (norm + 1e-8f);
  for (int k = 0; k < 4; ++k) u[tid + k*256] = y[tid + k*256]*inv;
  if (tid == 0) {
    float sigma = norm*norm*inv;
    scale_out[0] = 0.99f / (sigma + 1e-8f);
  }
}

// ---------------- fp32 -> fp16 convert ----------------
__global__ __launch_bounds__(256) void k_conv(const float* __restrict__ src,
                                              f16* __restrict__ dst, int n4) {
  int i = blockIdx.x*256 + threadIdx.x;
  if (i < n4) {
    float4 v = ((const float4*)src)[i];
    f16x4 h = { (f16)v.x, (f16)v.y, (f16)v.z, (f16)v.w };
    *(f16x4*)(dst + (size_t)i*4) = h;
  }
}

// ---------------- setup: h[0] rows (valid data, not sentinel) ----------------
__global__ __launch_bounds__(256) void k_setup(const float* __restrict__ h0,
                                               f16* __restrict__ h16,
                                               float* __restrict__ hout) {
  int g = blockIdx.x*256 + threadIdx.x;
  if (g < BATCH*DIM) { float v = h0[g]; hout[g] = v; h16[g] = (f16)v; }
}

// ---------------- sentinel-fill h16[1..2048] (64 MB) ----------------
__global__ __launch_bounds__(256) void k_sent(f16* __restrict__ h16) {
  const size_t i = (size_t)blockIdx.x*256 + threadIdx.x;   // one dwordx4 each
  uint4 s; s.x = SENT32; s.y = SENT32; s.z = SENT32; s.w = SENT32;
  ((uint4*)(h16 + BATCH*DIM))[i] = s;
}

// ---------------- fp16 MFMA GEMM: C[m,n] = sum_k A[m,k]*Bw[n,k] ----------------
__global__ __launch_bounds__(256) void k_gemm(const f16* __restrict__ A,
                                              const f16* __restrict__ Bw,
                                              int mode,
                                              f16* __restrict__ px_out,
                                              const float* __restrict__ bias,
                                              const float* __restrict__ z,
                                              const float* __restrict__ hf,
                                              float* __restrict__ outp) {
  const int tid = threadIdx.x;
  const int lane = tid & 63, wave = tid >> 6;
  const int nb = blockIdx.x & 7, mb = blockIdx.x >> 3;
  const int m0 = mb*128 + (wave >> 1)*64;
  const int n0 = nb*128 + (wave & 1)*64;
  const int fr = lane & 15;
  const int kq = (lane >> 4) * 8;
  const f16* pA = A  + (size_t)(m0 + fr)*1024 + kq;
  const f16* pB = Bw + (size_t)(n0 + fr)*1024 + kq;
  f32x4 acc[4][4] = {};
  for (int k0 = 0; k0 < 1024; k0 += 32) {
    f16x8 a[4], b[4];
    #pragma unroll
    for (int i = 0; i < 4; ++i) a[i] = *(const f16x8*)(pA + (size_t)i*16*1024 + k0);
    #pragma unroll
    for (int j = 0; j < 4; ++j) b[j] = *(const f16x8*)(pB + (size_t)j*16*1024 + k0);
    #pragma unroll
    for (int i = 0; i < 4; ++i)
      #pragma unroll
      for (int j = 0; j < 4; ++j)
        acc[i][j] = __builtin_amdgcn_mfma_f32_16x16x32_f16(a[i], b[j], acc[i][j], 0, 0, 0);
  }
  const int crow0 = (lane >> 4) * 4;
  const int ccol  = lane & 15;
  #pragma unroll
  for (int i = 0; i < 4; ++i)
    #pragma unroll
    for (int j = 0; j < 4; ++j) {
      const int col = n0 + j*16 + ccol;
      #pragma unroll
      for (int r = 0; r < 4; ++r) {
        const int row = m0 + i*16 + crow0 + r;
        const size_t idx = (size_t)row*1024 + col;
        const float val = acc[i][j][r];
        if (mode == 0) {
          px_out[idx] = (f16)(val + bias[col]);
        } else {
          float g = 1.0f / (1.0f + __expf(-(z[idx] + val)));
          outp[idx] = hf[idx + 16384] * g;
        }
      }
    }
}

// ---------------- persistent recurrence kernel -------------------------------
// Data-flow sync: NO stamps. h16[t] slots are pre-filled with the f16-NaN
// sentinel 0x7FFF7FFF; a producer's packed dword store of tanh outputs
// (always in [-1,1]) IS the ready signal. Consumers poll exactly the 32 bytes
// they need (per-lane done flags -> a lane stops loading a dword the moment
// it's valid). This removes the round-1..2 stamp round trip: producer
// s_waitcnt(0) drain + stamp store + 128-dword stamp polls per wave, which
// was a second dependent MALL round trip per step plus TB/s of poll traffic.
// All traffic remains relaxed agent-scope (sc-flag loads/stores at the
// coherence point) -- per-XCD L2s are not cross-coherent on gfx950.
__global__ __launch_bounds__(256) void k_chain(const float* __restrict__ Wh,
                                               const float* __restrict__ scale_p,
                                               const f16* __restrict__ px,
                                               f16* __restrict__ h16,
                                               float* __restrict__ hout) {
  const int tid = threadIdx.x;
  const int lane = tid & 63;
  const int wave = tid >> 6;
  const int wg = blockIdx.x;
  const int b = wg & 15;
  const int chunk = wg >> 4;       // 0..31
  const float scale = scale_p[0];

  // rows chunk*32+wave*8 .. +8; per-lane k-slices [lane*8, lane*8+8) and +512
  f16x2 wra[8][4], wrb[8][4];
  {
    const int r0 = chunk*32 + wave*8;
    #pragma unroll
    for (int i = 0; i < 8; ++i) {
      const float* src = Wh + (size_t)(r0+i)*1024 + lane*8;
      float4 a0 = *(const float4*)(src);
      float4 a1 = *(const float4*)(src+4);
      float4 b0 = *(const float4*)(src+512);
      float4 b1 = *(const float4*)(src+516);
      wra[i][0] = f16x2{(f16)(a0.x*scale), (f16)(a0.y*scale)};
      wra[i][1] = f16x2{(f16)(a0.z*scale), (f16)(a0.w*scale)};
      wra[i][2] = f16x2{(f16)(a1.x*scale), (f16)(a1.y*scale)};
      wra[i][3] = f16x2{(f16)(a1.z*scale), (f16)(a1.w*scale)};
      wrb[i][0] = f16x2{(f16)(b0.x*scale), (f16)(b0.y*scale)};
      wrb[i][1] = f16x2{(f16)(b0.z*scale), (f16)(b0.w*scale)};
      wrb[i][2] = f16x2{(f16)(b1.x*scale), (f16)(b1.y*scale)};
      wrb[i][3] = f16x2{(f16)(b1.z*scale), (f16)(b1.w*scale)};
    }
  }

  int budget = 4000000;   // converts a deadlock bug into fast-wrong

  for (int t = 0; t < T_STEPS; ++t) {
    const int rowbase = (t*16 + b) << 10;

    // px prefetch: independent of h(t), issue before the poll so its latency
    // hides under the wait.
    float pxv = 0.f;
    if (lane < 8) pxv = (float)px[rowbase + chunk*32 + wave*8 + lane];

    // wait: poll the exact h(t) bytes this lane consumes.
    unsigned long long* hq = (unsigned long long*)(h16 + rowbase);
    union HU { unsigned long long q; f16x2 p[2]; } a0, a1, b0, b1;
    a0.q = 0; a1.q = 0; b0.q = 0; b1.q = 0;
    bool r0 = false, r1 = false, r2 = false, r3 = false;
    while (true) {
      if (!r0) { a0.q = __hip_atomic_load(hq + 2*lane,       __ATOMIC_RELAXED, SCOPE_AGENT); r0 = valid8(a0.q); }
      if (!r1) { a1.q = __hip_atomic_load(hq + 2*lane + 1,   __ATOMIC_RELAXED, SCOPE_AGENT); r1 = valid8(a1.q); }
      if (!r2) { b0.q = __hip_atomic_load(hq + 128 + 2*lane,     __ATOMIC_RELAXED, SCOPE_AGENT); r2 = valid8(b0.q); }
      if (!r3) { b1.q = __hip_atomic_load(hq + 128 + 2*lane + 1, __ATOMIC_RELAXED, SCOPE_AGENT); r3 = valid8(b1.q); }
      if (__ballot((int)(!(r0 & r1 & r2 & r3))) == 0ull) break;
      if (--budget < 0) break;
      __builtin_amdgcn_s_sleep(1);
    }

    float res = 0.f;
    #pragma unroll
    for (int i = 0; i < 8; ++i) {
      float acc = 0.f;
      acc = fdot2f(wra[i][0], a0.p[0], acc);
      acc = fdot2f(wra[i][1], a0.p[1], acc);
      acc = fdot2f(wra[i][2], a1.p[0], acc);
      acc = fdot2f(wra[i][3], a1.p[1], acc);
      acc = fdot2f(wrb[i][0], b0.p[0], acc);
      acc = fdot2f(wrb[i][1], b0.p[1], acc);
      acc = fdot2f(wrb[i][2], b1.p[0], acc);
      acc = fdot2f(wrb[i][3], b1.p[1], acc);
      acc = dpp_add_f<0xB1>(acc);    // xor1 (quad_perm 1,0,3,2)
      acc = dpp_add_f<0x4E>(acc);    // xor2 (quad_perm 2,3,0,1)
      acc = dpp_add_f<0x141>(acc);   // row_half_mirror (quad<->quad)
      acc = dpp_add_f<0x140>(acc);   // row_mirror (8-half<->8-half)
      acc += __shfl_xor(acc, 16, 64);
      acc += __shfl_xor(acc, 32, 64);
      res = (lane == i) ? acc : res;
    }
    float hv = fast_tanh(res + pxv);      // valid on lanes 0..7
    float hvn = dpp_mov_xor1(hv);         // neighbor's value for dword packing
    const int gbase = (((t+1)*16 + b) << 10) + chunk*32 + wave*8;
    if (lane < 8) {
      // publish the signal (h16 dword) FIRST -- it is the consumers' gate.
      if (!(lane & 1)) {
        union { f16x2 h2; int i32; } pk;
        pk.h2 = f16x2{(f16)hv, (f16)hvn};
        __hip_atomic_store((int*)(h16 + gbase + lane), pk.i32,
                           __ATOMIC_RELAXED, SCOPE_AGENT);
      }
      hout[gbase + lane] = hv;
    }
  }
}

// ---------------- launcher ----------------
extern "C" void kernel_launch(void* const* d_in, const int* in_sizes, int n_in,
                              void* d_out, int out_size, void* d_ws, size_t ws_size,
                              hipStream_t stream) {
  (void)in_sizes; (void)n_in; (void)out_size; (void)ws_size;
  const float* x    = (const float*)d_in[0];
  const float* z    = (const float*)d_in[1];
  const float* h0   = (const float*)d_in[2];
  const float* Wx   = (const float*)d_in[3];
  const float* Wh   = (const float*)d_in[4];
  const float* Wg   = (const float*)d_in[5];
  const float* bias = (const float*)d_in[6];
  float* outs = (float*)d_out;
  float* hout = outs + (size_t)T_STEPS*BATCH*DIM;
  char* ws = (char*)d_ws;
  float* u      = (float*)(ws + OFF_U);
  float* v      = (float*)(ws + OFF_V);
  float* y      = (float*)(ws + OFF_Y);
  float* scale  = (float*)(ws + OFF_SCALE);
  float* part   = (float*)(ws + OFF_PART);
  f16* wx16 = (f16*)(ws + OFF_WX16);
  f16* wg16 = (f16*)(ws + OFF_WG16);
  f16* x16  = (f16*)(ws + OFF_X16);
  f16* px16 = (f16*)(ws + OFF_PX16);
  f16* h16  = (f16*)(ws + OFF_H16);

  k_ugen<<<1, 256, 0, stream>>>(u);
  for (int it = 0; it < 3; ++it) {
    k_mvT<<<64, 256, 0, stream>>>(Wh, u, part);
    k_norm_part<<<1, 256, 0, stream>>>(part, v);
    k_mv_rows<<<64, 256, 0, stream>>>(Wh, v, y);
    k_norm_u<<<1, 256, 0, stream>>>(y, u, scale);
  }
  k_conv<<<32768, 256, 0, stream>>>(x, x16, 8388608);
  k_conv<<<1024, 256, 0, stream>>>(Wx, wx16, 262144);
  k_conv<<<1024, 256, 0, stream>>>(Wg, wg16, 262144);
  k_setup<<<64, 256, 0, stream>>>(h0, h16, hout);
  // sentinel-fill h16[1..2048]: 2048*16*1024*2B / 16B = 4194304 uint4 stores
  k_sent<<<16384, 256, 0, stream>>>(h16);
  // px = x @ Wx^T + b  (fp16, bias folded)
  k_gemm<<<2048, 256, 0, stream>>>(x16, wx16, 0, px16, bias, nullptr, nullptr, nullptr);
  // sequential scan (data-flow sync via sentinel)
  k_chain<<<512, 256, 0, stream>>>(Wh, scale, px16, h16, hout);
  // out = h[t+1] * sigmoid(z + h[t+1] @ Wg^T)
  k_gemm<<<2048, 256, 0, stream>>>(h16 + BATCH*DIM, wg16, 1, nullptr, nullptr, z, hout, outs);
}